// Round 11
// baseline (125.151 us; speedup 1.0000x reference)
//
#include <hip/hip_runtime.h>

#define N_FEAT 1024
#define N_LAYER 4

// Algebra: xi = A_i*x0 + C_i, C_i = sum_{j<i} b_j (row-independent).
//   p_i = <x0,w_i>, e_i = <C_i,w_i>; A_{i+1} = A_i*(1+p_i) + e_i;
//   out = A_4*x0 + csum.
//
// Phase2-shaped FUSED kernel (the one clean untested configuration).
// Evidence: elementwise/fill shapes (massive TLP, tiny state, no per-wave
// machinery) run 6.5-8.6 TB/s; every fused variant sat at ~4.4 TB/s, and
// every prior attempt at this shape was confounded (R7/R8: launch_bounds
// cap -> spill, proven by FETCH/WRITE inflation; R9: 8-wave barrier
// lockstep; R6: DMA/vmcnt machinery at quartered batch). This version:
//  - ONE row per wave: xv[4] (16 VGPR) + p[4] + e[4] -> ~60 VGPR natural,
//    NO __launch_bounds__ min-waves cap (the proven spill-inducer), no
//    barriers, no DMA, no inline asm. Nothing to lockstep, nothing to spill.
//  - w (16 KB) + csum (4 KB) in LDS per block, written redundantly by each
//    wave (identical bits -> benign race, wave reads own writes; proven in
//    R7/R8 which PASSED). 20 KB/block -> up to 8 blocks/CU.
//  - 4096 blocks x 4 waves = 16384 row-waves: phase2's grid shape.
//  - per-byte overhead identical to R0: 24 shuffles / 4 KB row.
// Validity check: WRITE ~65 MB, FETCH 33-70 MB, VGPR <= ~100 (no scratch).
__global__ __launch_bounds__(256) void crossnet_kernel(
    const float* __restrict__ x,
    const float* __restrict__ weight_w,
    const float* __restrict__ weight_b,
    float* __restrict__ out,
    int n_rows) {
  const int wave = threadIdx.x >> 6;   // 0..3
  const int lane = threadIdx.x & 63;

  __shared__ float4 w_lds[N_LAYER * 256];  // [layer][col] 16 KB
  __shared__ float4 csum_lds[256];         // 4 KB

  // ---- preamble (per wave, redundant, barrier-free): w->LDS, csum->LDS, e ----
  float e[N_LAYER] = {0.f, 0.f, 0.f, 0.f};
#pragma unroll
  for (int c = 0; c < 4; ++c) {
    const int col = c * 64 + lane;
    float4 wv[N_LAYER];
#pragma unroll
    for (int i = 0; i < N_LAYER; ++i) {
      wv[i] = ((const float4*)(weight_w + i * N_FEAT))[col];
      w_lds[i * 256 + col] = wv[i];
    }
    float4 cum = make_float4(0.f, 0.f, 0.f, 0.f);
#pragma unroll
    for (int i = 0; i < N_LAYER; ++i) {
      if (i > 0)
        e[i] += cum.x * wv[i].x + cum.y * wv[i].y +
                cum.z * wv[i].z + cum.w * wv[i].w;
      const float4 b = ((const float4*)(weight_b + i * N_FEAT))[col];
      cum.x += b.x; cum.y += b.y; cum.z += b.z; cum.w += b.w;
    }
    csum_lds[col] = cum;
  }
#pragma unroll
  for (int off = 32; off > 0; off >>= 1)
#pragma unroll
    for (int i = 1; i < N_LAYER; ++i) e[i] += __shfl_xor(e[i], off, 64);

  // ---- this wave's single row ----
  const int row = blockIdx.x * 4 + wave;
  if (row >= n_rows) return;

  const float4* xq = (const float4*)x;   // row stride = 256 float4
  float4* oq = (float4*)out;

  // 4 independent float4 loads (full row across the wave)
  float4 xv[4];
#pragma unroll
  for (int c = 0; c < 4; ++c)
    xv[c] = xq[(size_t)row * 256 + c * 64 + lane];

  // ---- dot phase: w from LDS (conflict-free b128), xv in regs ----
  float p[N_LAYER] = {0.f, 0.f, 0.f, 0.f};
#pragma unroll
  for (int c = 0; c < 4; ++c) {
    const int col = c * 64 + lane;
#pragma unroll
    for (int i = 0; i < N_LAYER; ++i) {
      const float4 wv = w_lds[i * 256 + col];
      p[i] += xv[c].x * wv.x + xv[c].y * wv.y +
              xv[c].z * wv.z + xv[c].w * wv.w;
    }
  }

  // ---- butterfly: 4 p-values, 6 steps (24 shuffles per 4 KB row) ----
#pragma unroll
  for (int off = 32; off > 0; off >>= 1)
#pragma unroll
    for (int i = 0; i < N_LAYER; ++i) p[i] += __shfl_xor(p[i], off, 64);

  // ---- recurrence + store ----
  float A = 1.f;
#pragma unroll
  for (int i = 0; i < N_LAYER; ++i) A += A * p[i] + e[i];

#pragma unroll
  for (int c = 0; c < 4; ++c) {
    const int col = c * 64 + lane;
    const float4 cs = csum_lds[col];
    float4 o;
    o.x = fmaf(xv[c].x, A, cs.x);
    o.y = fmaf(xv[c].y, A, cs.y);
    o.z = fmaf(xv[c].z, A, cs.z);
    o.w = fmaf(xv[c].w, A, cs.w);
    oq[(size_t)row * 256 + col] = o;
  }
}

extern "C" void kernel_launch(void* const* d_in, const int* in_sizes, int n_in,
                              void* d_out, int out_size, void* d_ws, size_t ws_size,
                              hipStream_t stream) {
  const float* x = (const float*)d_in[0];
  const float* ww = (const float*)d_in[1];
  const float* wb = (const float*)d_in[2];
  float* out = (float*)d_out;

  const int n_rows = in_sizes[0] / N_FEAT;            // 16384
  const int rows_per_block = 4;                       // 4 waves x 1 row
  const int n_blocks = (n_rows + rows_per_block - 1) / rows_per_block;  // 4096
  crossnet_kernel<<<n_blocks, 256, 0, stream>>>(x, ww, wb, out, n_rows);
}